// Round 4
// baseline (317.736 us; speedup 1.0000x reference)
//
#include <hip/hip_runtime.h>
#include <hip/hip_bf16.h>

// FrequencyLayer: separable real DFT via bf16 MFMA.
// real[b,c,u,v] = sum_{i,j} x[i,j] cos(2pi(j*u+i*v)/N)
// imag[b,c,u,v] = -sum_{i,j} x[i,j] sin(2pi(j*u+i*v)/N), N=256, u,v in [0,128)
//
// v4 (from v3's counters: all pipes <15% busy, VALU-heavy f2bf, 1-deep prefetch):
//  - f32->bf16 via v_cvt_pk_bf16_f32 (HW RNE, 1 op / 2 elems; was ~4 ops/elem)
//  - 2-deep register prefetch for X (phase B) and tables (phase D)
//  - phase-D MFMA grouped so dependent same-acc pairs are >=7 insts apart
//  - s_setprio(1) around MFMA bursts

typedef __attribute__((ext_vector_type(8))) short short8;   // 8 bf16 = 4 VGPR (MFMA A/B frag)
typedef __attribute__((ext_vector_type(4))) short bf16x4;   // 4 bf16 = 8B (ds_write_b64)
typedef __attribute__((ext_vector_type(4))) float f32x4;    // MFMA C/D frag

typedef union { short8 s8; unsigned u[4]; } pk8;
typedef union { bf16x4 s4; unsigned u[2]; } pk4;

#define NN 256
#define KF 128
#define NIMG 1024

__device__ __align__(16) short g_Ct[KF * NN];   // cos(2pi*u*j/256)
__device__ __align__(16) short g_St[KF * NN];   // sin(2pi*u*j/256)
__device__ __align__(16) short g_Stn[KF * NN];  // -sin(2pi*u*j/256)

__device__ __forceinline__ short f2bf(float f) {
    union { float f; unsigned u; } v; v.f = f;
    unsigned r = v.u + 0x7FFFu + ((v.u >> 16) & 1u);  // RNE
    return (short)(r >> 16);
}

__device__ __forceinline__ unsigned cvtpk(float lo, float hi) {
    unsigned r;
    asm("v_cvt_pk_bf16_f32 %0, %1, %2" : "=v"(r) : "v"(lo), "v"(hi));
    return r;
}

__global__ void gen_tables() {
    int tid = blockIdx.x * blockDim.x + threadIdx.x;
    if (tid >= KF * NN) return;
    int u = tid >> 8;
    int j = tid & 255;
    int phase = (u * j) & 255;                       // exploit periodicity, exact angle
    float ang = (float)phase * 0.02454369260617026f; // 2pi/256
    float s, c;
    sincosf(ang, &s, &c);
    g_Ct[tid]  = f2bf(c);
    g_St[tid]  = f2bf(s);
    g_Stn[tid] = f2bf(-s);
}

#define MFMA(a, b, c) __builtin_amdgcn_mfma_f32_16x16x32_bf16(a, b, c, 0, 0, 0)

__global__ __launch_bounds__(512, 4) void freq_dft(const float* __restrict__ x,
                                                   float* __restrict__ out) {
    // LDS (64KB), two lifetimes:
    //   phase A/B: Ct half-slice [64][256] bf16 swizzled (32KB) | Stn half-slice (32KB)
    //   phase C/D: A1T [64u][256i] bf16 swizzled (32KB) | B1n (32KB)
    __shared__ __align__(16) char lds[65536];

    // XCD-pairing decode: both h-half blocks of one image land on the same XCD.
    const int bid = blockIdx.x;
    const int cc  = bid & 7;
    const int q   = bid >> 3;
    const int h   = q & 1;
    const int img = cc + ((q >> 1) << 3);

    const float* __restrict__ X = x + (size_t)img * (NN * NN);
    float* __restrict__ outR = out + (size_t)img * (KF * KF);
    float* __restrict__ outI = outR + (size_t)NIMG * (KF * KF);

    const int lane = threadIdx.x & 63;
    const int wave = threadIdx.x >> 6;   // 0..7
    const int l15  = lane & 15;
    const int lk8  = (lane >> 4) << 3;   // A/B frag k-base (shorts)
    const int lr4  = (lane >> 4) << 2;   // D frag row-base

    // ---------------- phase A: tables -> LDS (swizzled write, linear global read) ----
    {
        const short* __restrict__ srcC = g_Ct  + h * 64 * NN;
        const short* __restrict__ srcS = g_Stn + h * 64 * NN;
        #pragma unroll
        for (int k = 0; k < 4; ++k) {
            int slot = threadIdx.x + k * 512;        // 16B-chunk index, 0..2047
            int row  = slot >> 5;                    // 0..63
            int chk  = slot & 31;                    // 16B chunk within row
            int byte = row * 512 + ((chk << 4) ^ ((row & 7) << 4));
            short8 vC = *(const short8*)(srcC + row * NN + chk * 8);
            short8 vS = *(const short8*)(srcS + row * NN + chk * 8);
            *(short8*)(lds + byte)         = vC;
            *(short8*)(lds + 32768 + byte) = vS;
        }
    }
    __syncthreads();

    // ---------------- phase B: stage 1, X 2-deep prefetch, tables from LDS ---------
    f32x4 accA[2][4], accB[2][4];    // [fi][fu] : D[i][u] fragments
    {
        const int i0 = wave * 32;    // this wave's i-slice (32 rows)
        #pragma unroll
        for (int fi = 0; fi < 2; ++fi)
            #pragma unroll
            for (int fu = 0; fu < 4; ++fu) {
                accA[fi][fu] = (f32x4){0.f, 0.f, 0.f, 0.f};
                accB[fi][fu] = (f32x4){0.f, 0.f, 0.f, 0.f};
            }
        const float* __restrict__ xp0 = X + (i0 + l15) * NN + lk8;
        const float* __restrict__ xp1 = X + (i0 + 16 + l15) * NN + lk8;
        f32x4 pb[2][4];
        pb[0][0] = *(const f32x4*)(xp0);      pb[0][1] = *(const f32x4*)(xp0 + 4);
        pb[0][2] = *(const f32x4*)(xp1);      pb[0][3] = *(const f32x4*)(xp1 + 4);
        pb[1][0] = *(const f32x4*)(xp0 + 32); pb[1][1] = *(const f32x4*)(xp0 + 36);
        pb[1][2] = *(const f32x4*)(xp1 + 32); pb[1][3] = *(const f32x4*)(xp1 + 36);
        #pragma unroll
        for (int jj = 0; jj < 8; ++jj) {
            const int j0 = jj * 32;
            f32x4 c0 = pb[jj & 1][0], c1 = pb[jj & 1][1];
            f32x4 c2 = pb[jj & 1][2], c3 = pb[jj & 1][3];
            if (jj < 6) {   // prefetch j-tile jj+2 into the slot just consumed
                pb[jj & 1][0] = *(const f32x4*)(xp0 + j0 + 64);
                pb[jj & 1][1] = *(const f32x4*)(xp0 + j0 + 68);
                pb[jj & 1][2] = *(const f32x4*)(xp1 + j0 + 64);
                pb[jj & 1][3] = *(const f32x4*)(xp1 + j0 + 68);
            }
            pk8 xb0, xb1;
            xb0.u[0] = cvtpk(c0[0], c0[1]); xb0.u[1] = cvtpk(c0[2], c0[3]);
            xb0.u[2] = cvtpk(c1[0], c1[1]); xb0.u[3] = cvtpk(c1[2], c1[3]);
            xb1.u[0] = cvtpk(c2[0], c2[1]); xb1.u[1] = cvtpk(c2[2], c2[3]);
            xb1.u[2] = cvtpk(c3[0], c3[1]); xb1.u[3] = cvtpk(c3[2], c3[3]);
            short8 ca[4], sa[4];
            #pragma unroll
            for (int fu = 0; fu < 4; ++fu) {
                int row  = fu * 16 + l15;
                int byte = row * 512 + (((j0 + lk8) * 2) ^ ((row & 7) << 4));
                ca[fu] = *(const short8*)(lds + byte);
                sa[fu] = *(const short8*)(lds + 32768 + byte);
            }
            __builtin_amdgcn_s_setprio(1);
            #pragma unroll
            for (int fu = 0; fu < 4; ++fu) {
                accA[0][fu] = MFMA(xb0.s8, ca[fu], accA[0][fu]);
                accA[1][fu] = MFMA(xb1.s8, ca[fu], accA[1][fu]);
                accB[0][fu] = MFMA(xb0.s8, sa[fu], accB[0][fu]);
                accB[1][fu] = MFMA(xb1.s8, sa[fu], accB[1][fu]);
            }
            __builtin_amdgcn_s_setprio(0);
        }
    }
    __syncthreads();   // all table reads done; LDS region can be overwritten

    // ---------------- phase C: A1T/B1n -> LDS (b64 writes, swizzled rows) ----------
    {
        const int i0 = wave * 32;
        #pragma unroll
        for (int fi = 0; fi < 2; ++fi)
            #pragma unroll
            for (int fu = 0; fu < 4; ++fu) {
                int ul    = fu * 16 + l15;           // local u row 0..63
                int ibase = i0 + fi * 16 + lr4;      // 4 consecutive i
                int byte  = ul * 512 + ((ibase * 2) ^ ((ul & 7) << 4));
                pk4 a4, b4;
                a4.u[0] = cvtpk(accA[fi][fu][0], accA[fi][fu][1]);
                a4.u[1] = cvtpk(accA[fi][fu][2], accA[fi][fu][3]);
                b4.u[0] = cvtpk(accB[fi][fu][0], accB[fi][fu][1]);
                b4.u[1] = cvtpk(accB[fi][fu][2], accB[fi][fu][3]);
                *(bf16x4*)(lds + byte)         = a4.s4;
                *(bf16x4*)(lds + 32768 + byte) = b4.s4;
            }
    }
    __syncthreads();

    // ---------------- phase D: stage 2, tables 2-deep prefetch from global ---------
    {
        const int wu = wave >> 2;        // 0..1 : u-slice of 32 within the half
        const int wv = wave & 3;         // 0..3 : v-slice of 32
        f32x4 accR[2][2], accI[2][2];    // [fu][fv]
        #pragma unroll
        for (int fu = 0; fu < 2; ++fu)
            #pragma unroll
            for (int fv = 0; fv < 2; ++fv) {
                accR[fu][fv] = (f32x4){0.f, 0.f, 0.f, 0.f};
                accI[fu][fv] = (f32x4){0.f, 0.f, 0.f, 0.f};
            }
        const short* __restrict__ tp[6];
        tp[0] = g_Ct  + (wv * 32 + l15) * NN + lk8;
        tp[1] = g_Ct  + (wv * 32 + 16 + l15) * NN + lk8;
        tp[2] = g_St  + (wv * 32 + l15) * NN + lk8;
        tp[3] = g_St  + (wv * 32 + 16 + l15) * NN + lk8;
        tp[4] = g_Stn + (wv * 32 + l15) * NN + lk8;
        tp[5] = g_Stn + (wv * 32 + 16 + l15) * NN + lk8;
        short8 tb[2][6];
        #pragma unroll
        for (int k = 0; k < 6; ++k) {
            tb[0][k] = *(const short8*)(tp[k]);
            tb[1][k] = *(const short8*)(tp[k] + 32);
        }
        #pragma unroll
        for (int ii = 0; ii < 8; ++ii) {
            const int is = ii * 32;
            short8 cb0 = tb[ii & 1][0], cb1 = tb[ii & 1][1];
            short8 sb0 = tb[ii & 1][2], sb1 = tb[ii & 1][3];
            short8 nb0 = tb[ii & 1][4], nb1 = tb[ii & 1][5];
            if (ii < 6) {   // prefetch k-tile ii+2
                #pragma unroll
                for (int k = 0; k < 6; ++k)
                    tb[ii & 1][k] = *(const short8*)(tp[k] + is + 64);
            }
            short8 a[2], bn[2];
            #pragma unroll
            for (int fu = 0; fu < 2; ++fu) {
                int ul   = wu * 32 + fu * 16 + l15;
                int byte = ul * 512 + (((is + lk8) * 2) ^ ((ul & 7) << 4));
                a[fu]  = *(const short8*)(lds + byte);
                bn[fu] = *(const short8*)(lds + 32768 + byte);
            }
            __builtin_amdgcn_s_setprio(1);
            // group 1: R += a*cb
            accR[0][0] = MFMA(a[0],  cb0, accR[0][0]);
            accR[1][0] = MFMA(a[1],  cb0, accR[1][0]);
            accR[0][1] = MFMA(a[0],  cb1, accR[0][1]);
            accR[1][1] = MFMA(a[1],  cb1, accR[1][1]);
            // group 2: I += bn*cb   (independent of group 1)
            accI[0][0] = MFMA(bn[0], cb0, accI[0][0]);
            accI[1][0] = MFMA(bn[1], cb0, accI[1][0]);
            accI[0][1] = MFMA(bn[0], cb1, accI[0][1]);
            accI[1][1] = MFMA(bn[1], cb1, accI[1][1]);
            // group 3: R += bn*sb   (dep on group 1, 7+ insts back)
            accR[0][0] = MFMA(bn[0], sb0, accR[0][0]);
            accR[1][0] = MFMA(bn[1], sb0, accR[1][0]);
            accR[0][1] = MFMA(bn[0], sb1, accR[0][1]);
            accR[1][1] = MFMA(bn[1], sb1, accR[1][1]);
            // group 4: I += a*nb    (dep on group 2, 7+ insts back)
            accI[0][0] = MFMA(a[0],  nb0, accI[0][0]);
            accI[1][0] = MFMA(a[1],  nb0, accI[1][0]);
            accI[0][1] = MFMA(a[0],  nb1, accI[0][1]);
            accI[1][1] = MFMA(a[1],  nb1, accI[1][1]);
            __builtin_amdgcn_s_setprio(0);
        }
        #pragma unroll
        for (int fu = 0; fu < 2; ++fu)
            #pragma unroll
            for (int fv = 0; fv < 2; ++fv)
                #pragma unroll
                for (int r = 0; r < 4; ++r) {
                    int u = h * 64 + wu * 32 + fu * 16 + lr4 + r;
                    int v = wv * 32 + fv * 16 + l15;
                    outR[u * KF + v] = accR[fu][fv][r];
                    outI[u * KF + v] = accI[fu][fv][r];
                }
    }
}

extern "C" void kernel_launch(void* const* d_in, const int* in_sizes, int n_in,
                              void* d_out, int out_size, void* d_ws, size_t ws_size,
                              hipStream_t stream) {
    const float* x = (const float*)d_in[0];
    float* out = (float*)d_out;
    gen_tables<<<dim3((KF * NN + 255) / 256), dim3(256), 0, stream>>>();
    freq_dft<<<dim3(NIMG * 2), dim3(512), 0, stream>>>(x, out);
}

// Round 6
// 234.669 us; speedup vs baseline: 1.3540x; 1.3540x over previous
//
#include <hip/hip_runtime.h>
#include <hip/hip_bf16.h>

// FrequencyLayer: separable real DFT via bf16 MFMA.
// real[b,c,u,v] = sum_{i,j} x[i,j] cos(2pi(j*u+i*v)/N)
// imag[b,c,u,v] = -sum_{i,j} x[i,j] sin(2pi(j*u+i*v)/N), N=256, u,v in [0,128)
//
// v6: structural split. v3's counters showed <25% of cycles in any pipe ->
// barrier-lockstep suspect. Two kernels:
//   stage1: X -> A1T/B1n (bf16), v3 phases A-C + coalesced copy-out.
//           Intermediate lives in the OUTPUT buffer (64KB/img slice each).
//   stage2: barrier-free streaming GEMM from L2/L3 (no LDS), one sync only
//           before the in-place epilogue overwrite.
// All numerics identical to v3 (f2bf; bf16 negate = sign-bit XOR, bit-exact).

typedef __attribute__((ext_vector_type(8))) short short8;   // 8 bf16 = 4 VGPR
typedef __attribute__((ext_vector_type(4))) short bf16x4;   // 4 bf16 = 8B
typedef __attribute__((ext_vector_type(4))) float f32x4;    // MFMA C/D frag

typedef union { short8 s8; unsigned u[4]; } pk8;            // scalar union (v4-proven)

#define NN 256
#define KF 128
#define NIMG 1024

__device__ __align__(16) short g_Ct[KF * NN];   // cos(2pi*u*j/256)
__device__ __align__(16) short g_St[KF * NN];   // sin(2pi*u*j/256)
__device__ __align__(16) short g_Stn[KF * NN];  // -sin(2pi*u*j/256)

__device__ __forceinline__ short f2bf(float f) {
    union { float f; unsigned u; } v; v.f = f;
    unsigned r = v.u + 0x7FFFu + ((v.u >> 16) & 1u);  // RNE
    return (short)(r >> 16);
}

__global__ void gen_tables() {
    int tid = blockIdx.x * blockDim.x + threadIdx.x;
    if (tid >= KF * NN) return;
    int u = tid >> 8;
    int j = tid & 255;
    int phase = (u * j) & 255;                       // exploit periodicity, exact angle
    float ang = (float)phase * 0.02454369260617026f; // 2pi/256
    float s, c;
    sincosf(ang, &s, &c);
    g_Ct[tid]  = f2bf(c);
    g_St[tid]  = f2bf(s);
    g_Stn[tid] = f2bf(-s);
}

#define MFMA(a, b, c) __builtin_amdgcn_mfma_f32_16x16x32_bf16(a, b, c, 0, 0, 0)

// ---------------- stage 1: X -> A1T/B1n (bf16) in output buffer ----------------
__global__ __launch_bounds__(512, 4) void dft_stage1(const float* __restrict__ x,
                                                     short* outbuf) {
    __shared__ __align__(16) char lds[65536];

    // XCD-pairing decode: both h-half blocks of one image land on the same XCD.
    const int bid = blockIdx.x;
    const int cc  = bid & 7;
    const int q   = bid >> 3;
    const int h   = q & 1;
    const int img = cc + ((q >> 1) << 3);

    const float* __restrict__ X = x + (size_t)img * (NN * NN);
    short* gA = outbuf + (size_t)img * 32768 + h * 64 * NN;          // A1T rows h*64..
    short* gB = outbuf + (size_t)(NIMG + img) * 32768 + h * 64 * NN; // B1n rows h*64..

    const int lane = threadIdx.x & 63;
    const int wave = threadIdx.x >> 6;   // 0..7
    const int l15  = lane & 15;
    const int lk8  = (lane >> 4) << 3;
    const int lr4  = (lane >> 4) << 2;

    // phase A: tables -> LDS (swizzled write, linear global read)
    {
        const short* __restrict__ srcC = g_Ct  + h * 64 * NN;
        const short* __restrict__ srcS = g_Stn + h * 64 * NN;
        #pragma unroll
        for (int k = 0; k < 4; ++k) {
            int slot = threadIdx.x + k * 512;        // 16B-chunk index, 0..2047
            int row  = slot >> 5;                    // 0..63
            int chk  = slot & 31;                    // 16B chunk within row
            int byte = row * 512 + ((chk << 4) ^ ((row & 7) << 4));
            short8 vC = *(const short8*)(srcC + row * NN + chk * 8);
            short8 vS = *(const short8*)(srcS + row * NN + chk * 8);
            *(short8*)(lds + byte)         = vC;
            *(short8*)(lds + 32768 + byte) = vS;
        }
    }
    __syncthreads();

    // phase B: stage-1 GEMM, X prefetched, tables from LDS
    f32x4 accA[2][4], accB[2][4];    // [fi][fu] : D[i][u] fragments
    {
        const int i0 = wave * 32;
        #pragma unroll
        for (int fi = 0; fi < 2; ++fi)
            #pragma unroll
            for (int fu = 0; fu < 4; ++fu) {
                accA[fi][fu] = (f32x4){0.f, 0.f, 0.f, 0.f};
                accB[fi][fu] = (f32x4){0.f, 0.f, 0.f, 0.f};
            }
        const float* __restrict__ xp0 = X + (i0 + l15) * NN + lk8;
        const float* __restrict__ xp1 = X + (i0 + 16 + l15) * NN + lk8;
        f32x4 nx0 = *(const f32x4*)(xp0);
        f32x4 nx1 = *(const f32x4*)(xp0 + 4);
        f32x4 nx2 = *(const f32x4*)(xp1);
        f32x4 nx3 = *(const f32x4*)(xp1 + 4);
        #pragma unroll
        for (int jj = 0; jj < 8; ++jj) {
            const int j0 = jj * 32;
            f32x4 c0 = nx0, c1 = nx1, c2 = nx2, c3 = nx3;
            if (jj < 7) {
                nx0 = *(const f32x4*)(xp0 + j0 + 32);
                nx1 = *(const f32x4*)(xp0 + j0 + 36);
                nx2 = *(const f32x4*)(xp1 + j0 + 32);
                nx3 = *(const f32x4*)(xp1 + j0 + 36);
            }
            short8 xb0, xb1;
            xb0[0] = f2bf(c0[0]); xb0[1] = f2bf(c0[1]); xb0[2] = f2bf(c0[2]); xb0[3] = f2bf(c0[3]);
            xb0[4] = f2bf(c1[0]); xb0[5] = f2bf(c1[1]); xb0[6] = f2bf(c1[2]); xb0[7] = f2bf(c1[3]);
            xb1[0] = f2bf(c2[0]); xb1[1] = f2bf(c2[1]); xb1[2] = f2bf(c2[2]); xb1[3] = f2bf(c2[3]);
            xb1[4] = f2bf(c3[0]); xb1[5] = f2bf(c3[1]); xb1[6] = f2bf(c3[2]); xb1[7] = f2bf(c3[3]);
            short8 ca[4], sa[4];
            #pragma unroll
            for (int fu = 0; fu < 4; ++fu) {
                int row  = fu * 16 + l15;
                int byte = row * 512 + (((j0 + lk8) * 2) ^ ((row & 7) << 4));
                ca[fu] = *(const short8*)(lds + byte);
                sa[fu] = *(const short8*)(lds + 32768 + byte);
            }
            #pragma unroll
            for (int fu = 0; fu < 4; ++fu) {
                accA[0][fu] = MFMA(xb0, ca[fu], accA[0][fu]);
                accA[1][fu] = MFMA(xb1, ca[fu], accA[1][fu]);
                accB[0][fu] = MFMA(xb0, sa[fu], accB[0][fu]);
                accB[1][fu] = MFMA(xb1, sa[fu], accB[1][fu]);
            }
        }
    }
    __syncthreads();   // table reads done; LDS region reused for A1T/B1n

    // phase C: D-frags -> LDS [u][i] bf16 (b64 writes, swizzled rows)
    {
        const int i0 = wave * 32;
        #pragma unroll
        for (int fi = 0; fi < 2; ++fi)
            #pragma unroll
            for (int fu = 0; fu < 4; ++fu) {
                int ul    = fu * 16 + l15;
                int ibase = i0 + fi * 16 + lr4;
                int byte  = ul * 512 + ((ibase * 2) ^ ((ul & 7) << 4));
                bf16x4 a4, b4;
                #pragma unroll
                for (int r = 0; r < 4; ++r) {
                    a4[r] = f2bf(accA[fi][fu][r]);
                    b4[r] = f2bf(accB[fi][fu][r]);
                }
                *(bf16x4*)(lds + byte)         = a4;
                *(bf16x4*)(lds + 32768 + byte) = b4;
            }
    }
    __syncthreads();

    // phase D': coalesced copy-out LDS -> global (unswizzle)
    {
        #pragma unroll
        for (int k = 0; k < 4; ++k) {
            int slot = threadIdx.x + k * 512;
            int row  = slot >> 5;
            int chk  = slot & 31;
            int byte = row * 512 + ((chk << 4) ^ ((row & 7) << 4));
            short8 vA = *(const short8*)(lds + byte);
            short8 vB = *(const short8*)(lds + 32768 + byte);
            *(short8*)(gA + row * NN + chk * 8) = vA;
            *(short8*)(gB + row * NN + chk * 8) = vB;
        }
    }
}

// ---------------- stage 2: barrier-free GEMM from L2/L3, in-place epilogue ------
__global__ __launch_bounds__(256, 4) void dft_stage2(float* out) {
    const int bid = blockIdx.x;
    const int img = bid >> 2;
    const int h   = (bid >> 1) & 1;
    const int wu  = bid & 1;

    // NOTE: gA/gB alias out (intermediate lives in the output buffer). No
    // __restrict__ here; one __syncthreads before the overwrite epilogue.
    const short* gA = (const short*)out + (size_t)img * 32768;
    const short* gB = (const short*)out + (size_t)(NIMG + img) * 32768;
    float* outR = out + (size_t)img * (KF * KF);
    float* outI = out + (size_t)(NIMG + img) * (KF * KF);

    const int lane = threadIdx.x & 63;
    const int wv   = threadIdx.x >> 6;   // 0..3 : v-slice of 32
    const int l15  = lane & 15;
    const int lk8  = (lane >> 4) << 3;
    const int lr4  = (lane >> 4) << 2;
    const int u0   = h * 64 + wu * 32;

    f32x4 accR[2][2], accI[2][2];        // [fu][fv]
    #pragma unroll
    for (int fu = 0; fu < 2; ++fu)
        #pragma unroll
        for (int fv = 0; fv < 2; ++fv) {
            accR[fu][fv] = (f32x4){0.f, 0.f, 0.f, 0.f};
            accI[fu][fv] = (f32x4){0.f, 0.f, 0.f, 0.f};
        }

    const short* pa0 = gA + (u0 + l15) * NN + lk8;
    const short* pa1 = gA + (u0 + 16 + l15) * NN + lk8;
    const short* pb0 = gB + (u0 + l15) * NN + lk8;
    const short* pb1 = gB + (u0 + 16 + l15) * NN + lk8;
    const short* tC0 = g_Ct + (wv * 32 + l15) * NN + lk8;
    const short* tC1 = g_Ct + (wv * 32 + 16 + l15) * NN + lk8;
    const short* tS0 = g_St + (wv * 32 + l15) * NN + lk8;
    const short* tS1 = g_St + (wv * 32 + 16 + l15) * NN + lk8;

    short8 aN0 = *(const short8*)pa0, aN1 = *(const short8*)pa1;
    short8 bN0 = *(const short8*)pb0, bN1 = *(const short8*)pb1;
    short8 cbN0 = *(const short8*)tC0, cbN1 = *(const short8*)tC1;
    short8 sbN0 = *(const short8*)tS0, sbN1 = *(const short8*)tS1;

    #pragma unroll
    for (int ii = 0; ii < 8; ++ii) {
        const int is = ii * 32;
        short8 a0 = aN0, a1 = aN1, bn0 = bN0, bn1 = bN1;
        short8 cb0 = cbN0, cb1 = cbN1, sb0 = sbN0, sb1 = sbN1;
        if (ii < 7) {   // 1-deep named prefetch of all 8 streams
            aN0  = *(const short8*)(pa0 + is + 32);
            aN1  = *(const short8*)(pa1 + is + 32);
            bN0  = *(const short8*)(pb0 + is + 32);
            bN1  = *(const short8*)(pb1 + is + 32);
            cbN0 = *(const short8*)(tC0 + is + 32);
            cbN1 = *(const short8*)(tC1 + is + 32);
            sbN0 = *(const short8*)(tS0 + is + 32);
            sbN1 = *(const short8*)(tS1 + is + 32);
        }
        // nb = -sb via sign-bit XOR (bit-exact vs f2bf(-s): RNE is symmetric)
        pk8 n0, n1;
        n0.s8 = sb0; n1.s8 = sb1;
        n0.u[0] ^= 0x80008000u; n0.u[1] ^= 0x80008000u;
        n0.u[2] ^= 0x80008000u; n0.u[3] ^= 0x80008000u;
        n1.u[0] ^= 0x80008000u; n1.u[1] ^= 0x80008000u;
        n1.u[2] ^= 0x80008000u; n1.u[3] ^= 0x80008000u;
        short8 nb0 = n0.s8, nb1 = n1.s8;
        // group 1: R += a*cb
        accR[0][0] = MFMA(a0,  cb0, accR[0][0]);
        accR[1][0] = MFMA(a1,  cb0, accR[1][0]);
        accR[0][1] = MFMA(a0,  cb1, accR[0][1]);
        accR[1][1] = MFMA(a1,  cb1, accR[1][1]);
        // group 2: I += bn*cb (independent)
        accI[0][0] = MFMA(bn0, cb0, accI[0][0]);
        accI[1][0] = MFMA(bn1, cb0, accI[1][0]);
        accI[0][1] = MFMA(bn0, cb1, accI[0][1]);
        accI[1][1] = MFMA(bn1, cb1, accI[1][1]);
        // group 3: R += bn*sb (dep on group 1, 8 insts back)
        accR[0][0] = MFMA(bn0, sb0, accR[0][0]);
        accR[1][0] = MFMA(bn1, sb0, accR[1][0]);
        accR[0][1] = MFMA(bn0, sb1, accR[0][1]);
        accR[1][1] = MFMA(bn1, sb1, accR[1][1]);
        // group 4: I += a*nb (dep on group 2, 8 insts back)
        accI[0][0] = MFMA(a0,  nb0, accI[0][0]);
        accI[1][0] = MFMA(a1,  nb0, accI[1][0]);
        accI[0][1] = MFMA(a0,  nb1, accI[0][1]);
        accI[1][1] = MFMA(a1,  nb1, accI[1][1]);
    }

    __syncthreads();   // all waves done READING gA/gB before any wave overwrites

    #pragma unroll
    for (int fu = 0; fu < 2; ++fu)
        #pragma unroll
        for (int fv = 0; fv < 2; ++fv)
            #pragma unroll
            for (int r = 0; r < 4; ++r) {
                int u = u0 + fu * 16 + lr4 + r;
                int v = wv * 32 + fv * 16 + l15;
                outR[u * KF + v] = accR[fu][fv][r];
                outI[u * KF + v] = accI[fu][fv][r];
            }
}

extern "C" void kernel_launch(void* const* d_in, const int* in_sizes, int n_in,
                              void* d_out, int out_size, void* d_ws, size_t ws_size,
                              hipStream_t stream) {
    const float* x = (const float*)d_in[0];
    float* out = (float*)d_out;
    gen_tables<<<dim3((KF * NN + 255) / 256), dim3(256), 0, stream>>>();
    dft_stage1<<<dim3(NIMG * 2), dim3(512), 0, stream>>>(x, (short*)out);
    dft_stage2<<<dim3(NIMG * 4), dim3(256), 0, stream>>>(out);
}

// Round 7
// 160.663 us; speedup vs baseline: 1.9777x; 1.4606x over previous
//
#include <hip/hip_runtime.h>
#include <hip/hip_bf16.h>

// FrequencyLayer: separable real DFT via bf16 MFMA.
// real[b,c,u,v] = sum_{i,j} x[i,j] cos(2pi(j*u+i*v)/N)
// imag[b,c,u,v] = -sum_{i,j} x[i,j] sin(2pi(j*u+i*v)/N), N=256, u,v in [0,128)
//
// v7 = v3 (proven 193us) + schedule-only deltas:
//  - 2-deep named-scalar prefetch in phase B (X) and phase D (tables)
//  - per-wave staggered loop start (wave w begins at tile (t+w)&7) to
//    decorrelate the 8 waves' load bursts (sum order-independent)
//  - phase D: 4 table streams only; nb = sb ^ 0x8000 (elementwise vector XOR,
//    bit-exact bf16 negate; stream trim verified in v6)
// Numerics otherwise identical to v3 (f2bf everywhere).

typedef __attribute__((ext_vector_type(8))) short short8;   // 8 bf16 = 4 VGPR
typedef __attribute__((ext_vector_type(4))) short bf16x4;   // 4 bf16 = 8B
typedef __attribute__((ext_vector_type(4))) float f32x4;    // MFMA C/D frag

#define NN 256
#define KF 128
#define NIMG 1024

__device__ __align__(16) short g_Ct[KF * NN];   // cos(2pi*u*j/256)
__device__ __align__(16) short g_St[KF * NN];   // sin(2pi*u*j/256)
__device__ __align__(16) short g_Stn[KF * NN];  // -sin(2pi*u*j/256)

__device__ __forceinline__ short f2bf(float f) {
    union { float f; unsigned u; } v; v.f = f;
    unsigned r = v.u + 0x7FFFu + ((v.u >> 16) & 1u);  // RNE
    return (short)(r >> 16);
}

__global__ void gen_tables() {
    int tid = blockIdx.x * blockDim.x + threadIdx.x;
    if (tid >= KF * NN) return;
    int u = tid >> 8;
    int j = tid & 255;
    int phase = (u * j) & 255;                       // exploit periodicity, exact angle
    float ang = (float)phase * 0.02454369260617026f; // 2pi/256
    float s, c;
    sincosf(ang, &s, &c);
    g_Ct[tid]  = f2bf(c);
    g_St[tid]  = f2bf(s);
    g_Stn[tid] = f2bf(-s);
}

#define MFMA(a, b, c) __builtin_amdgcn_mfma_f32_16x16x32_bf16(a, b, c, 0, 0, 0)

__global__ __launch_bounds__(512, 4) void freq_dft(const float* __restrict__ x,
                                                   float* __restrict__ out) {
    // LDS (64KB), two lifetimes:
    //   phase A/B: Ct half-slice [64][256] bf16 swizzled (32KB) | Stn half-slice (32KB)
    //   phase C/D: A1T [64u][256i] bf16 swizzled (32KB) | B1n (32KB)
    __shared__ __align__(16) char lds[65536];

    // XCD-pairing decode: both h-half blocks of one image land on the same XCD.
    const int bid = blockIdx.x;
    const int cc  = bid & 7;
    const int q   = bid >> 3;
    const int h   = q & 1;
    const int img = cc + ((q >> 1) << 3);

    const float* __restrict__ X = x + (size_t)img * (NN * NN);
    float* __restrict__ outR = out + (size_t)img * (KF * KF);
    float* __restrict__ outI = outR + (size_t)NIMG * (KF * KF);

    const int lane = threadIdx.x & 63;
    const int wave = threadIdx.x >> 6;   // 0..7
    const int l15  = lane & 15;
    const int lk8  = (lane >> 4) << 3;   // A/B frag k-base (shorts)
    const int lr4  = (lane >> 4) << 2;   // D frag row-base

    // ---------------- phase A: tables -> LDS (swizzled write, linear global read) ----
    {
        const short* __restrict__ srcC = g_Ct  + h * 64 * NN;
        const short* __restrict__ srcS = g_Stn + h * 64 * NN;
        #pragma unroll
        for (int k = 0; k < 4; ++k) {
            int slot = threadIdx.x + k * 512;        // 16B-chunk index, 0..2047
            int row  = slot >> 5;                    // 0..63
            int chk  = slot & 31;                    // 16B chunk within row
            int byte = row * 512 + ((chk << 4) ^ ((row & 7) << 4));
            short8 vC = *(const short8*)(srcC + row * NN + chk * 8);
            short8 vS = *(const short8*)(srcS + row * NN + chk * 8);
            *(short8*)(lds + byte)         = vC;
            *(short8*)(lds + 32768 + byte) = vS;
        }
    }
    __syncthreads();

    // ---------------- phase B: stage 1, staggered start, 2-deep X prefetch ---------
    f32x4 accA[2][4], accB[2][4];    // [fi][fu] : D[i][u] fragments
    {
        const int i0 = wave * 32;    // this wave's i-slice (32 rows)
        #pragma unroll
        for (int fi = 0; fi < 2; ++fi)
            #pragma unroll
            for (int fu = 0; fu < 4; ++fu) {
                accA[fi][fu] = (f32x4){0.f, 0.f, 0.f, 0.f};
                accB[fi][fu] = (f32x4){0.f, 0.f, 0.f, 0.f};
            }
        const float* __restrict__ xp0 = X + (i0 + l15) * NN + lk8;
        const float* __restrict__ xp1 = X + (i0 + 16 + l15) * NN + lk8;
        const int wst = wave;                         // stagger offset
        const int jA  = (wst & 7) * 32;
        const int jB  = ((wst + 1) & 7) * 32;
        // 2-deep pipeline: A = tile t, B = tile t+1, load tile t+2 at iter t.
        f32x4 a0 = *(const f32x4*)(xp0 + jA), a1 = *(const f32x4*)(xp0 + jA + 4);
        f32x4 a2 = *(const f32x4*)(xp1 + jA), a3 = *(const f32x4*)(xp1 + jA + 4);
        f32x4 b0 = *(const f32x4*)(xp0 + jB), b1 = *(const f32x4*)(xp0 + jB + 4);
        f32x4 b2 = *(const f32x4*)(xp1 + jB), b3 = *(const f32x4*)(xp1 + jB + 4);
        #pragma unroll
        for (int t = 0; t < 8; ++t) {
            const int j0 = ((t + wst) & 7) * 32;
            f32x4 c0 = a0, c1 = a1, c2 = a2, c3 = a3;
            a0 = b0; a1 = b1; a2 = b2; a3 = b3;
            if (t < 6) {   // issue tile t+2 load (2 iterations ahead of consumption)
                const int jn = ((t + 2 + wst) & 7) * 32;
                b0 = *(const f32x4*)(xp0 + jn); b1 = *(const f32x4*)(xp0 + jn + 4);
                b2 = *(const f32x4*)(xp1 + jn); b3 = *(const f32x4*)(xp1 + jn + 4);
            }
            short8 xb0, xb1;
            xb0[0] = f2bf(c0[0]); xb0[1] = f2bf(c0[1]); xb0[2] = f2bf(c0[2]); xb0[3] = f2bf(c0[3]);
            xb0[4] = f2bf(c1[0]); xb0[5] = f2bf(c1[1]); xb0[6] = f2bf(c1[2]); xb0[7] = f2bf(c1[3]);
            xb1[0] = f2bf(c2[0]); xb1[1] = f2bf(c2[1]); xb1[2] = f2bf(c2[2]); xb1[3] = f2bf(c2[3]);
            xb1[4] = f2bf(c3[0]); xb1[5] = f2bf(c3[1]); xb1[6] = f2bf(c3[2]); xb1[7] = f2bf(c3[3]);
            short8 ca[4], sa[4];
            #pragma unroll
            for (int fu = 0; fu < 4; ++fu) {
                int row  = fu * 16 + l15;
                int byte = row * 512 + (((j0 + lk8) * 2) ^ ((row & 7) << 4));
                ca[fu] = *(const short8*)(lds + byte);
                sa[fu] = *(const short8*)(lds + 32768 + byte);
            }
            #pragma unroll
            for (int fu = 0; fu < 4; ++fu) {
                accA[0][fu] = MFMA(xb0, ca[fu], accA[0][fu]);
                accA[1][fu] = MFMA(xb1, ca[fu], accA[1][fu]);
                accB[0][fu] = MFMA(xb0, sa[fu], accB[0][fu]);
                accB[1][fu] = MFMA(xb1, sa[fu], accB[1][fu]);
            }
        }
    }
    __syncthreads();   // all table reads done; LDS region can be overwritten

    // ---------------- phase C: A1T/B1n -> LDS (b64 writes, swizzled rows) ----------
    {
        const int i0 = wave * 32;
        #pragma unroll
        for (int fi = 0; fi < 2; ++fi)
            #pragma unroll
            for (int fu = 0; fu < 4; ++fu) {
                int ul    = fu * 16 + l15;           // local u row 0..63
                int ibase = i0 + fi * 16 + lr4;      // 4 consecutive i
                int byte  = ul * 512 + ((ibase * 2) ^ ((ul & 7) << 4));
                bf16x4 a4, b4;
                #pragma unroll
                for (int r = 0; r < 4; ++r) {
                    a4[r] = f2bf(accA[fi][fu][r]);
                    b4[r] = f2bf(accB[fi][fu][r]);
                }
                *(bf16x4*)(lds + byte)         = a4;
                *(bf16x4*)(lds + 32768 + byte) = b4;
            }
    }
    __syncthreads();

    // ---------------- phase D: stage 2, staggered, 2-deep table prefetch -----------
    {
        const int wu = wave >> 2;        // 0..1 : u-slice of 32 within the half
        const int wv = wave & 3;         // 0..3 : v-slice of 32
        const short8 smask = {(short)0x8000, (short)0x8000, (short)0x8000, (short)0x8000,
                              (short)0x8000, (short)0x8000, (short)0x8000, (short)0x8000};
        f32x4 accR[2][2], accI[2][2];    // [fu][fv]
        #pragma unroll
        for (int fu = 0; fu < 2; ++fu)
            #pragma unroll
            for (int fv = 0; fv < 2; ++fv) {
                accR[fu][fv] = (f32x4){0.f, 0.f, 0.f, 0.f};
                accI[fu][fv] = (f32x4){0.f, 0.f, 0.f, 0.f};
            }
        const short* __restrict__ tC0 = g_Ct + (wv * 32 + l15) * NN + lk8;
        const short* __restrict__ tC1 = g_Ct + (wv * 32 + 16 + l15) * NN + lk8;
        const short* __restrict__ tS0 = g_St + (wv * 32 + l15) * NN + lk8;
        const short* __restrict__ tS1 = g_St + (wv * 32 + 16 + l15) * NN + lk8;
        const int wst = wave;
        const int iA  = (wst & 7) * 32;
        const int iB  = ((wst + 1) & 7) * 32;
        short8 ac0 = *(const short8*)(tC0 + iA), ac1 = *(const short8*)(tC1 + iA);
        short8 as0 = *(const short8*)(tS0 + iA), as1 = *(const short8*)(tS1 + iA);
        short8 bc0 = *(const short8*)(tC0 + iB), bc1 = *(const short8*)(tC1 + iB);
        short8 bs0 = *(const short8*)(tS0 + iB), bs1 = *(const short8*)(tS1 + iB);
        #pragma unroll
        for (int t = 0; t < 8; ++t) {
            const int is = ((t + wst) & 7) * 32;
            short8 cb0 = ac0, cb1 = ac1, sb0 = as0, sb1 = as1;
            ac0 = bc0; ac1 = bc1; as0 = bs0; as1 = bs1;
            if (t < 6) {   // issue tile t+2 table loads
                const int in = ((t + 2 + wst) & 7) * 32;
                bc0 = *(const short8*)(tC0 + in); bc1 = *(const short8*)(tC1 + in);
                bs0 = *(const short8*)(tS0 + in); bs1 = *(const short8*)(tS1 + in);
            }
            // nb = -sb via elementwise sign-bit XOR (bit-exact bf16 negate)
            short8 nb0 = sb0 ^ smask;
            short8 nb1 = sb1 ^ smask;
            short8 a[2], bn[2];
            #pragma unroll
            for (int fu = 0; fu < 2; ++fu) {
                int ul   = wu * 32 + fu * 16 + l15;
                int byte = ul * 512 + (((is + lk8) * 2) ^ ((ul & 7) << 4));
                a[fu]  = *(const short8*)(lds + byte);
                bn[fu] = *(const short8*)(lds + 32768 + byte);
            }
            // group 1: R += a*cb
            accR[0][0] = MFMA(a[0],  cb0, accR[0][0]);
            accR[1][0] = MFMA(a[1],  cb0, accR[1][0]);
            accR[0][1] = MFMA(a[0],  cb1, accR[0][1]);
            accR[1][1] = MFMA(a[1],  cb1, accR[1][1]);
            // group 2: I += bn*cb (independent of group 1)
            accI[0][0] = MFMA(bn[0], cb0, accI[0][0]);
            accI[1][0] = MFMA(bn[1], cb0, accI[1][0]);
            accI[0][1] = MFMA(bn[0], cb1, accI[0][1]);
            accI[1][1] = MFMA(bn[1], cb1, accI[1][1]);
            // group 3: R += bn*sb (dep on group 1, 8 insts back)
            accR[0][0] = MFMA(bn[0], sb0, accR[0][0]);
            accR[1][0] = MFMA(bn[1], sb0, accR[1][0]);
            accR[0][1] = MFMA(bn[0], sb1, accR[0][1]);
            accR[1][1] = MFMA(bn[1], sb1, accR[1][1]);
            // group 4: I += a*nb (dep on group 2, 8 insts back)
            accI[0][0] = MFMA(a[0],  nb0, accI[0][0]);
            accI[1][0] = MFMA(a[1],  nb0, accI[1][0]);
            accI[0][1] = MFMA(a[0],  nb1, accI[0][1]);
            accI[1][1] = MFMA(a[1],  nb1, accI[1][1]);
        }
        #pragma unroll
        for (int fu = 0; fu < 2; ++fu)
            #pragma unroll
            for (int fv = 0; fv < 2; ++fv)
                #pragma unroll
                for (int r = 0; r < 4; ++r) {
                    int u = h * 64 + wu * 32 + fu * 16 + lr4 + r;
                    int v = wv * 32 + fv * 16 + l15;
                    outR[u * KF + v] = accR[fu][fv][r];
                    outI[u * KF + v] = accI[fu][fv][r];
                }
    }
}

extern "C" void kernel_launch(void* const* d_in, const int* in_sizes, int n_in,
                              void* d_out, int out_size, void* d_ws, size_t ws_size,
                              hipStream_t stream) {
    const float* x = (const float*)d_in[0];
    float* out = (float*)d_out;
    gen_tables<<<dim3((KF * NN + 255) / 256), dim3(256), 0, stream>>>();
    freq_dft<<<dim3(NIMG * 2), dim3(512), 0, stream>>>(x, out);
}